// Round 12
// baseline (184.567 us; speedup 1.0000x reference)
//
#include <hip/hip_runtime.h>
#include <hip/hip_bf16.h>

#define BB 2
#define SS 2048
#define DD 1024
#define HH 16
#define HD 64
#define MM (BB*SS)   // 4096 rows

typedef __attribute__((ext_vector_type(8))) short bf16x8;
typedef __attribute__((ext_vector_type(4))) float f32x4;
typedef __attribute__((ext_vector_type(16))) float f32x16;

#define QSCALE 0.18033688f   // 0.125 * log2(e) — folded into Q; softmax in log2 domain

static __device__ __forceinline__ unsigned short f2bf(float f) {
    unsigned int u = __builtin_bit_cast(unsigned int, f);
    u += 0x7fffu + ((u >> 16) & 1u);
    return (unsigned short)(u >> 16);
}

static __device__ __forceinline__ void gload16(const unsigned short* g, unsigned short* l) {
    __builtin_amdgcn_global_load_lds(
        (const __attribute__((address_space(1))) unsigned int*)g,
        (__attribute__((address_space(3))) unsigned int*)l, 16, 0, 0);
}

// ---------------------------------------------------------------------------
// prep: bid<2048 -> x fp32->bf16; else weight transpose-convert [k][n]->[n][k]
// ---------------------------------------------------------------------------
__global__ __launch_bounds__(256) void prep_kernel(const float* __restrict__ x,
                                                   const float* __restrict__ W0,
                                                   const float* __restrict__ W1,
                                                   const float* __restrict__ W2,
                                                   const float* __restrict__ W3,
                                                   unsigned short* __restrict__ xb,
                                                   unsigned short* __restrict__ Wt)
{
    const int t = threadIdx.x;
    const int bid = blockIdx.x;
    if (bid < 2048) {
        const size_t i = ((size_t)bid * 256 + t) * 8;
        float4 a = *(const float4*)(x + i);
        float4 b = *(const float4*)(x + i + 4);
        union { unsigned short u[8]; bf16x8 v; } pk;
        pk.u[0] = f2bf(a.x); pk.u[1] = f2bf(a.y); pk.u[2] = f2bf(a.z); pk.u[3] = f2bf(a.w);
        pk.u[4] = f2bf(b.x); pk.u[5] = f2bf(b.y); pk.u[6] = f2bf(b.z); pk.u[7] = f2bf(b.w);
        *(bf16x8*)(xb + i) = pk.v;
        return;
    }
    __shared__ unsigned short Ts[64][72];
    const int wsel = (bid - 2048) >> 8;
    const int rem  = (bid - 2048) & 255;
    const float* W = wsel == 0 ? W0 : wsel == 1 ? W1 : wsel == 2 ? W2 : W3;
    unsigned short* out = Wt + (size_t)wsel * DD * DD;
    const int n0 = (rem & 15) * 64, k0 = (rem >> 4) * 64;
#pragma unroll
    for (int i = 0; i < 4; ++i) {
        const int r = (t >> 4) + i * 16;
        const int c = (t & 15) * 4;
        float4 v = *(const float4*)(W + (size_t)(k0 + r) * DD + n0 + c);
        Ts[c + 0][r] = f2bf(v.x); Ts[c + 1][r] = f2bf(v.y);
        Ts[c + 2][r] = f2bf(v.z); Ts[c + 3][r] = f2bf(v.w);
    }
    __syncthreads();
#pragma unroll
    for (int j = 0; j < 2; ++j) {
        const int ch = j * 256 + t;
        const int rn = ch >> 3, ck = (ch & 7) * 8;
        bf16x8 v = *(const bf16x8*)&Ts[rn][ck];
        *(bf16x8*)(out + (size_t)(n0 + rn) * DD + k0 + ck) = v;
    }
}

// ---------------------------------------------------------------------------
// MFMA GEMM v4t + XCD 4x4-supertile swizzle (T1, correctly oriented).
// Core (verified r6/r10/r11): BM x 128 tile, BK=64 (16 iters), XOR-swizzled
// LDS, double-buffered 2-phase pipeline (stage t+1 before compute of t;
// single vmcnt drain per tile). Structure search CLOSED (BK=32, counted
// vmcnt, 8-phase all null/negative at this shape).
// NEW (isolating r1's confounded T1 test, with the RIGHT orientation):
// launch id -> XCD c = id&7 (HW round-robin); each XCD owns nwg/128
// supertiles of 16 blocks (4m x 4n). Working set per supertile = 4 A-panels
// + 4 B-panels = 2MB < 4MB L2; each panel L2-reused 4x (vs L3-class reuse
// in the default n-major order). Targets the per-barrier drain latency
// (L3 ~450cy -> L2 ~200cy) + shrinks exposure to harness-fill contention.
// Bijective: requires gx%4==0, gy%4==0, nwg%128==0 (QKV 768, out-proj 512 ok).
// Mechanical signature to check: QKV FETCH_SIZE 33 -> ~22-26MB.
// mode 0: N=3072 fused QKV (Q scaled by QSCALE, V transposed [b,h,d,s])
// mode 1: N=1024 out-proj -> fp32 [M,D]
// ---------------------------------------------------------------------------
template<int BM>
__global__ __launch_bounds__(256) void gemm_mfma(const unsigned short* __restrict__ A,
                                                 const unsigned short* __restrict__ Bt,
                                                 const float* __restrict__ bias0,
                                                 const float* __restrict__ bias1,
                                                 const float* __restrict__ bias2,
                                                 unsigned short* __restrict__ Qb,
                                                 unsigned short* __restrict__ Kb,
                                                 unsigned short* __restrict__ Vb,
                                                 float* __restrict__ outf,
                                                 int mode)
{
    constexpr int MT = BM / 32;          // m-frags per wave
    constexpr int NA = BM / 32;          // A chunks per thread (4 @128, 2 @64)

    __shared__ unsigned short As[2][BM * 64];
    __shared__ unsigned short Bs[2][128 * 64];

    const int t = threadIdx.x;
    const int w = t >> 6, l = t & 63;
    const int lane16 = l & 15, quad = l >> 4;

    // ---- XCD 4x4-supertile decode ----
    const int gx = gridDim.x;                      // m-tiles
    const int id = blockIdx.y * gx + blockIdx.x;   // launch-linear (x fastest)
    const int c  = id & 7;                         // XCD (HW round-robin)
    const int q  = id >> 3;                        // 0..nwg/8-1
    const int sl = q >> 4, inner = q & 15;         // supertile-local, block-in-st
    const int im = inner & 3, in_ = inner >> 2;
    const int sgx = gx >> 2;                       // supertile grid x
    const int sgrp = c * ((gridDim.x * gridDim.y) >> 7) + sl;   // nwg/128 st/XCD
    const int mtile = (sgrp % sgx) * 4 + im;
    const int ntile = (sgrp / sgx) * 4 + in_;
    const int m0 = mtile * BM, n0 = ntile * 128;

    const int wm = (w & 1) * (BM / 2), wn = (w >> 1) * 64;

    f32x4 acc[MT][4] = {};

    // staging decode (NA A-chunks + 4 B-chunks per thread)
    int arow[NA], akcg[NA];
#pragma unroll
    for (int j = 0; j < NA; ++j) {
        const int cc = t + j * 256;
        arow[j] = cc >> 3;
        akcg[j] = (cc & 7) ^ (arow[j] & 7);
    }
    int srow[4], skcg[4];
#pragma unroll
    for (int j = 0; j < 4; ++j) {
        const int cc = t + j * 256;
        srow[j] = cc >> 3;
        skcg[j] = (cc & 7) ^ (srow[j] & 7);
    }

    // prologue: stage tile 0 into buffer 0, then one drain+barrier
#pragma unroll
    for (int j = 0; j < NA; ++j)
        gload16(A + (size_t)(m0 + arow[j]) * DD + akcg[j] * 8, &As[0][(t + j * 256) * 8]);
#pragma unroll
    for (int j = 0; j < 4; ++j)
        gload16(Bt + (size_t)(n0 + srow[j]) * DD + skcg[j] * 8, &Bs[0][(t + j * 256) * 8]);
    __syncthreads();

#pragma unroll 2
    for (int kt = 0; kt < 16; ++kt) {
        const int cur = kt & 1;
        // issue next tile's stage FIRST — latency hides under this tile's compute
        if (kt + 1 < 16) {
            const int k1 = (kt + 1) * 64;
#pragma unroll
            for (int j = 0; j < NA; ++j)
                gload16(A + (size_t)(m0 + arow[j]) * DD + k1 + akcg[j] * 8, &As[cur ^ 1][(t + j * 256) * 8]);
#pragma unroll
            for (int j = 0; j < 4; ++j)
                gload16(Bt + (size_t)(n0 + srow[j]) * DD + k1 + skcg[j] * 8, &Bs[cur ^ 1][(t + j * 256) * 8]);
        }
        // compute tile kt from buf[cur]
#pragma unroll
        for (int h = 0; h < 2; ++h) {
            bf16x8 af[MT], bfr[4];
#pragma unroll
            for (int mt = 0; mt < MT; ++mt) {
                const int row = wm + mt * 16 + lane16;
                af[mt] = *(const bf16x8*)&As[cur][(row * 8 + ((h * 4 + quad) ^ (row & 7))) * 8];
            }
#pragma unroll
            for (int nt = 0; nt < 4; ++nt) {
                const int row = wn + nt * 16 + lane16;
                bfr[nt] = *(const bf16x8*)&Bs[cur][(row * 8 + ((h * 4 + quad) ^ (row & 7))) * 8];
            }
#pragma unroll
            for (int mt = 0; mt < MT; ++mt)
#pragma unroll
                for (int nt = 0; nt < 4; ++nt)
                    acc[mt][nt] = __builtin_amdgcn_mfma_f32_16x16x32_bf16(af[mt], bfr[nt], acc[mt][nt], 0, 0, 0);
        }
        __syncthreads();
    }

    if (mode == 0) {
        const int which = n0 >> 10;
        const float* bias = which == 0 ? bias0 : which == 1 ? bias1 : bias2;
#pragma unroll
        for (int nt = 0; nt < 4; ++nt) {
            const int gcol = n0 + wn + nt * 16 + lane16;
            const int cd = gcol & 1023;
            const float bv = bias[cd];
            const int h_ = cd >> 6, d = cd & 63;
            if (which == 2) {
#pragma unroll
                for (int mt = 0; mt < MT; ++mt) {
                    const int row0 = m0 + wm + mt * 16 + quad * 4;
                    const int b_ = row0 >> 11, s0 = row0 & 2047;
                    union { unsigned short u[4]; uint2 v; } pk;
#pragma unroll
                    for (int r = 0; r < 4; ++r) pk.u[r] = f2bf(acc[mt][nt][r] + bv);
                    *(uint2*)(Vb + ((size_t)(b_ * HH + h_) * HD + d) * SS + s0) = pk.v;
                }
            } else {
                unsigned short* dst3 = which == 0 ? Qb : Kb;
                const float sc_ = which == 0 ? QSCALE : 1.0f;
#pragma unroll
                for (int mt = 0; mt < MT; ++mt)
#pragma unroll
                    for (int r = 0; r < 4; ++r) {
                        const int row = m0 + wm + mt * 16 + quad * 4 + r;
                        const int b_ = row >> 11, s_ = row & 2047;
                        dst3[(((size_t)(b_ * HH + h_) * SS + s_) * HD) + d] =
                            f2bf((acc[mt][nt][r] + bv) * sc_);
                    }
            }
        }
    } else {
#pragma unroll
        for (int nt = 0; nt < 4; ++nt) {
            const int gcol = n0 + wn + nt * 16 + lane16;
            const float bv = bias0[gcol];
#pragma unroll
            for (int mt = 0; mt < MT; ++mt)
#pragma unroll
                for (int r = 0; r < 4; ++r) {
                    const int row = m0 + wm + mt * 16 + quad * 4 + r;
                    outf[(size_t)row * DD + gcol] = acc[mt][nt][r] + bv;
                }
        }
    }
}

// ---------------------------------------------------------------------------
// MFMA flash attention v10 (verified r11, unchanged): T14 reg-staged K/V
// ring with LDS-only barriers; 32x32x16 swapped-operand MFMA; in-register
// softmax (T12 cvt_pk+permlane); fixed-max log2 softmax; parity k-split;
// softmax denominator on the MFMA pipe (ones-trick).
// ---------------------------------------------------------------------------
__global__ __launch_bounds__(512) void attn_mfma(const unsigned short* __restrict__ Q,
                                                 const unsigned short* __restrict__ K,
                                                 const unsigned short* __restrict__ V,
                                                 unsigned short* __restrict__ ctx)
{
    __shared__ unsigned short Ks[4][4096];   // [tile&3][row 64][8 chunks swizzled]
    __shared__ unsigned short Vs[4][4096];   // [tile&3][d 64][8 chunks swizzled]

    const int t = threadIdx.x;
    const int w = t >> 6, l = t & 63;
    const int l31 = l & 31, hi = l >> 5;
    const int qg = w & 3, par = w >> 2;            // q-group, k-parity
    const int bid = blockIdx.x;
    const int halfg = bid >> 8, idx = bid & 255;
    const int qb_ = idx >> 5;                      // 0..7
    const int qblk = halfg ? qb_ : 15 - qb_;       // pair (15-k, k) per CU
    const int hb = idx & 31;
    const int h = hb & 15, b = hb >> 4;
    const int q0 = qblk * 128;
    const size_t bh = (size_t)(b * HH + h) * SS;
    const unsigned short* Vg = V + (size_t)(b * HH + h) * HD * SS;

    const int wq0 = q0 + qg * 32;                  // this q-group's 32 rows
    // Q B-frags: lane holds Q[wq0 + l31][dt*16 + hi*8 .. +7]
    bf16x8 qf[4];
#pragma unroll
    for (int dt = 0; dt < 4; ++dt)
        qf[dt] = *(const bf16x8*)(Q + (bh + wq0 + l31) * HD + dt * 16 + hi * 8);

    // all-ones bf16 A-frag for the l-reduction MFMA
    bf16x8 ones;
#pragma unroll
    for (int i = 0; i < 8; ++i) ones[i] = (short)0x3F80;

    f32x16 ot[2] = {};                             // O^T: [d-half][16 regs], q = l31
    f32x16 lacc = {};                              // l: all 16 regs equal, col = l31

    const int ntiles = 2 * qblk + 2;               // always even
    // staging: 512 chunks of 16B per (tensor,tile), exactly 1 per thread
    const int sr = t >> 3;                         // row (K) / d (V)
    const int sg = (t & 7) ^ (sr & 7);             // swizzled k-chunk

    {   // prologue: reg-load + ds_write tiles 0 and 1
        uint4 ka  = *(const uint4*)(K + (bh + sr) * HD + sg * 8);
        uint4 kb2 = *(const uint4*)(K + (bh + 64 + sr) * HD + sg * 8);
        uint4 va  = *(const uint4*)(Vg + (size_t)sr * SS + sg * 8);
        uint4 vb2 = *(const uint4*)(Vg + (size_t)sr * SS + 64 + sg * 8);
        *(uint4*)&Ks[0][t * 8] = ka;
        *(uint4*)&Ks[1][t * 8] = kb2;
        *(uint4*)&Vs[0][t * 8] = va;
        *(uint4*)&Vs[1][t * 8] = vb2;
    }
    asm volatile("s_waitcnt lgkmcnt(0)" ::: "memory");
    __builtin_amdgcn_sched_barrier(0);
    __builtin_amdgcn_s_barrier();

    const int nsup = ntiles >> 1;
    for (int st = 0; st < nsup; ++st) {
        // (a) issue next 2 tiles' global loads into registers — no wait
        uint4 ka, kb2, va, vb2;
        const bool pre = (2 * st + 2 < ntiles);
        if (pre) {
            const int kaof = (2 * st + 2) * 64, kbof = kaof + 64;
            ka  = *(const uint4*)(K + (bh + kaof + sr) * HD + sg * 8);
            kb2 = *(const uint4*)(K + (bh + kbof + sr) * HD + sg * 8);
            va  = *(const uint4*)(Vg + (size_t)sr * SS + kaof + sg * 8);
            vb2 = *(const uint4*)(Vg + (size_t)sr * SS + kbof + sg * 8);
        }
        __builtin_amdgcn_sched_barrier(0);         // pin: loads issued before compute

        // (b) compute this wave's parity tile from the ring
        const int mt = 2 * st + par;
        const int k0 = mt * 64;
        if (k0 <= wq0 + 31) {                      // not fully causal-masked
            const unsigned short* Kt = Ks[mt & 3];
            const unsigned short* Vt = Vs[mt & 3];

            // S^T = K Q (log2-scaled already); two 32-k halves interleaved
            f32x16 s[2] = {};
            __builtin_amdgcn_s_setprio(1);
#pragma unroll
            for (int dt = 0; dt < 4; ++dt) {
#pragma unroll
                for (int kh = 0; kh < 2; ++kh) {
                    const int row = kh * 32 + l31;
                    bf16x8 kf = *(const bf16x8*)&Kt[(row * 8 + ((dt * 2 + hi) ^ (row & 7))) * 8];
                    s[kh] = __builtin_amdgcn_mfma_f32_32x32x16_bf16(kf, qf[dt], s[kh], 0, 0, 0);
                }
            }
            __builtin_amdgcn_s_setprio(0);

            // causal mask on diagonal tiles: k = k0 + kh*32 + (r&3)+8*(r>>2)+4*hi
            if (k0 + 63 > wq0) {
                const int q = wq0 + l31;
#pragma unroll
                for (int kh = 0; kh < 2; ++kh)
#pragma unroll
                    for (int r = 0; r < 16; ++r) {
                        const int k = k0 + kh * 32 + (r & 3) + 8 * (r >> 2) + 4 * hi;
                        if (k > q) s[kh][r] = -1e30f;
                    }
            }

            // p = exp2(s) in place (sum deferred to the ones-MFMA)
#pragma unroll
            for (int kh = 0; kh < 2; ++kh)
#pragma unroll
                for (int r = 0; r < 16; ++r) s[kh][r] = __builtin_amdgcn_exp2f(s[kh][r]);

            // P -> A-frag redistribution (T12) + PV + l, per 16-k chunk
#pragma unroll
            for (int kh = 0; kh < 2; ++kh) {
#pragma unroll
                for (int c = 0; c < 2; ++c) {
                    const int rb = c * 8;
                    unsigned int w0, w1, w2, w3;
                    asm("v_cvt_pk_bf16_f32 %0, %1, %2" : "=v"(w0) : "v"(s[kh][rb + 0]), "v"(s[kh][rb + 1]));
                    asm("v_cvt_pk_bf16_f32 %0, %1, %2" : "=v"(w2) : "v"(s[kh][rb + 4]), "v"(s[kh][rb + 5]));
                    asm("v_cvt_pk_bf16_f32 %0, %1, %2" : "=v"(w1) : "v"(s[kh][rb + 2]), "v"(s[kh][rb + 3]));
                    asm("v_cvt_pk_bf16_f32 %0, %1, %2" : "=v"(w3) : "v"(s[kh][rb + 6]), "v"(s[kh][rb + 7]));
                    asm("v_permlane32_swap_b32 %0, %1" : "+v"(w0), "+v"(w2));
                    asm("v_permlane32_swap_b32 %0, %1" : "+v"(w1), "+v"(w3));
                    union { unsigned int u[4]; bf16x8 v; } pa;
                    pa.u[0] = w0; pa.u[1] = w1; pa.u[2] = w2; pa.u[3] = w3;
                    const int chunk = kh * 4 + c * 2 + hi;
                    const int rlo = l31, rhi2 = 32 + l31;
                    bf16x8 v0 = *(const bf16x8*)&Vt[(rlo * 8 + (chunk ^ (rlo & 7))) * 8];
                    bf16x8 v1 = *(const bf16x8*)&Vt[(rhi2 * 8 + (chunk ^ (rhi2 & 7))) * 8];
                    __builtin_amdgcn_s_setprio(1);
                    ot[0] = __builtin_amdgcn_mfma_f32_32x32x16_bf16(v0, pa.v, ot[0], 0, 0, 0);
                    ot[1] = __builtin_amdgcn_mfma_f32_32x32x16_bf16(v1, pa.v, ot[1], 0, 0, 0);
                    lacc  = __builtin_amdgcn_mfma_f32_32x32x16_bf16(ones, pa.v, lacc, 0, 0, 0);
                    __builtin_amdgcn_s_setprio(0);
                }
            }
        }

        // (c) write staged regs to the ring (vmcnt wait auto-inserted here,
        //     hidden under the compute above), then LDS-only barrier
        if (pre) {
            const int ba = (2 * st + 2) & 3, bb3 = (2 * st + 3) & 3;
            *(uint4*)&Ks[ba][t * 8] = ka;
            *(uint4*)&Ks[bb3][t * 8] = kb2;
            *(uint4*)&Vs[ba][t * 8] = va;
            *(uint4*)&Vs[bb3][t * 8] = vb2;
        }
        asm volatile("s_waitcnt lgkmcnt(0)" ::: "memory");
        __builtin_amdgcn_sched_barrier(0);
        __builtin_amdgcn_s_barrier();
    }

    // l for this wave's tiles: any reg of lacc (all 16 equal; both halves full)
    float lp = lacc[0];

    // ---- parity combine: O_total = O_p0 + O_p1, l_total = l_p0 + l_p1 ----
    float* Osh = (float*)&Ks[0][0];                // 4 qg x 32 regs x 64 lanes = 32KB
    float* Lsh = (float*)&Vs[0][0];                // 4 qg x 64 lanes
    if (par == 1) {
#pragma unroll
        for (int a2 = 0; a2 < 2; ++a2)
#pragma unroll
            for (int r = 0; r < 16; ++r) Osh[qg * 2048 + (a2 * 16 + r) * 64 + l] = ot[a2][r];
        Lsh[qg * 64 + l] = lp;
    }
    __syncthreads();
    if (par == 0) {
#pragma unroll
        for (int a2 = 0; a2 < 2; ++a2)
#pragma unroll
            for (int r = 0; r < 16; ++r) ot[a2][r] += Osh[qg * 2048 + (a2 * 16 + r) * 64 + l];
        lp += Lsh[qg * 64 + l];

        const float inv = 1.f / lp;

        const int qrow = wq0 + l31;
        unsigned short* dst = ctx + ((size_t)(b * SS) + qrow) * DD + h * HD;
#pragma unroll
        for (int a2 = 0; a2 < 2; ++a2)
#pragma unroll
            for (int u = 0; u < 4; ++u) {
                const int d0 = a2 * 32 + 8 * u + 4 * hi;
                union { unsigned short u4[4]; uint2 v; } pk;
#pragma unroll
                for (int r = 0; r < 4; ++r) pk.u4[r] = f2bf(ot[a2][4 * u + r] * inv);
                *(uint2*)(dst + d0) = pk.v;
            }
    }
}

// ---------------------------------------------------------------------------
extern "C" void kernel_launch(void* const* d_in, const int* in_sizes, int n_in,
                              void* d_out, int out_size, void* d_ws, size_t ws_size,
                              hipStream_t stream) {
    const float* x  = (const float*)d_in[0];
    const float* Wq = (const float*)d_in[1];
    const float* bq = (const float*)d_in[2];
    const float* Wk = (const float*)d_in[3];
    const float* bk = (const float*)d_in[4];
    const float* Wv = (const float*)d_in[5];
    const float* bv = (const float*)d_in[6];
    const float* Wo = (const float*)d_in[7];
    const float* bo = (const float*)d_in[8];
    float* out = (float*)d_out;

    unsigned short* xb  = (unsigned short*)d_ws;
    unsigned short* Wt  = xb  + (size_t)MM * DD;
    unsigned short* Qb  = Wt  + (size_t)4 * DD * DD;
    unsigned short* Kb  = Qb  + (size_t)MM * DD;
    unsigned short* Vb  = Kb  + (size_t)MM * DD;
    unsigned short* ctxb = Vb + (size_t)MM * DD;

    prep_kernel<<<2048 + 1024, 256, 0, stream>>>(x, Wq, Wk, Wv, Wo, xb, Wt);

    gemm_mfma<128><<<dim3(MM / 128, 3072 / 128), 256, 0, stream>>>(
        xb, Wt, bq, bk, bv, Qb, Kb, Vb, nullptr, 0);

    attn_mfma<<<(SS / 128) * HH * BB, 512, 0, stream>>>(Qb, Kb, Vb, ctxb);

    gemm_mfma<64><<<dim3(MM / 64, DD / 128), 256, 0, stream>>>(
        ctxb, Wt + (size_t)3 * DD * DD, bo, nullptr, nullptr,
        nullptr, nullptr, nullptr, out, 1);
}

// Round 13
// 181.527 us; speedup vs baseline: 1.0167x; 1.0167x over previous
//
#include <hip/hip_runtime.h>
#include <hip/hip_bf16.h>

#define BB 2
#define SS 2048
#define DD 1024
#define HH 16
#define HD 64
#define MM (BB*SS)   // 4096 rows

typedef __attribute__((ext_vector_type(8))) short bf16x8;
typedef __attribute__((ext_vector_type(4))) float f32x4;
typedef __attribute__((ext_vector_type(16))) float f32x16;

#define QSCALE 0.18033688f   // 0.125 * log2(e) — folded into Q; softmax in log2 domain

static __device__ __forceinline__ unsigned short f2bf(float f) {
    unsigned int u = __builtin_bit_cast(unsigned int, f);
    u += 0x7fffu + ((u >> 16) & 1u);
    return (unsigned short)(u >> 16);
}

static __device__ __forceinline__ void gload16(const unsigned short* g, unsigned short* l) {
    __builtin_amdgcn_global_load_lds(
        (const __attribute__((address_space(1))) unsigned int*)g,
        (__attribute__((address_space(3))) unsigned int*)l, 16, 0, 0);
}

// ---------------------------------------------------------------------------
// prep: bid<2048 -> x fp32->bf16; else weight transpose-convert [k][n]->[n][k]
// ---------------------------------------------------------------------------
__global__ __launch_bounds__(256) void prep_kernel(const float* __restrict__ x,
                                                   const float* __restrict__ W0,
                                                   const float* __restrict__ W1,
                                                   const float* __restrict__ W2,
                                                   const float* __restrict__ W3,
                                                   unsigned short* __restrict__ xb,
                                                   unsigned short* __restrict__ Wt)
{
    const int t = threadIdx.x;
    const int bid = blockIdx.x;
    if (bid < 2048) {
        const size_t i = ((size_t)bid * 256 + t) * 8;
        float4 a = *(const float4*)(x + i);
        float4 b = *(const float4*)(x + i + 4);
        union { unsigned short u[8]; bf16x8 v; } pk;
        pk.u[0] = f2bf(a.x); pk.u[1] = f2bf(a.y); pk.u[2] = f2bf(a.z); pk.u[3] = f2bf(a.w);
        pk.u[4] = f2bf(b.x); pk.u[5] = f2bf(b.y); pk.u[6] = f2bf(b.z); pk.u[7] = f2bf(b.w);
        *(bf16x8*)(xb + i) = pk.v;
        return;
    }
    __shared__ unsigned short Ts[64][72];
    const int wsel = (bid - 2048) >> 8;
    const int rem  = (bid - 2048) & 255;
    const float* W = wsel == 0 ? W0 : wsel == 1 ? W1 : wsel == 2 ? W2 : W3;
    unsigned short* out = Wt + (size_t)wsel * DD * DD;
    const int n0 = (rem & 15) * 64, k0 = (rem >> 4) * 64;
#pragma unroll
    for (int i = 0; i < 4; ++i) {
        const int r = (t >> 4) + i * 16;
        const int c = (t & 15) * 4;
        float4 v = *(const float4*)(W + (size_t)(k0 + r) * DD + n0 + c);
        Ts[c + 0][r] = f2bf(v.x); Ts[c + 1][r] = f2bf(v.y);
        Ts[c + 2][r] = f2bf(v.z); Ts[c + 3][r] = f2bf(v.w);
    }
    __syncthreads();
#pragma unroll
    for (int j = 0; j < 2; ++j) {
        const int ch = j * 256 + t;
        const int rn = ch >> 3, ck = (ch & 7) * 8;
        bf16x8 v = *(const bf16x8*)&Ts[rn][ck];
        *(bf16x8*)(out + (size_t)(n0 + rn) * DD + k0 + ck) = v;
    }
}

// ---------------------------------------------------------------------------
// MFMA GEMM v4t (r11 verified best): BM x 128 tile, BK=64 (16 iters),
// XOR-swizzled LDS, double-buffered 2-phase pipeline (stage t+1 before
// compute of t; single vmcnt drain per tile at the barrier).
// Structure search CLOSED: BK=32 (r5) -19%; counted-vmcnt ring-4 (r9) null;
// T1 XCD swizzle r1 (confounded) and r12 (clean, correctly-oriented 4x4
// supertiles) BOTH regressed — FETCH rose, locality games don't pay with
// A+B L3-resident. 8-phase 256² grid-mismatched at N=3072 (192 blocks).
// mode 0 (BM=128): N=3072 fused QKV (Q scaled, V transposed [b,h,d,s])
// mode 1 (BM=64):  N=1024 out-proj -> fp32 [M,D]; 512 blocks = 2/CU (r11 win)
// ---------------------------------------------------------------------------
template<int BM>
__global__ __launch_bounds__(256) void gemm_mfma(const unsigned short* __restrict__ A,
                                                 const unsigned short* __restrict__ Bt,
                                                 const float* __restrict__ bias0,
                                                 const float* __restrict__ bias1,
                                                 const float* __restrict__ bias2,
                                                 unsigned short* __restrict__ Qb,
                                                 unsigned short* __restrict__ Kb,
                                                 unsigned short* __restrict__ Vb,
                                                 float* __restrict__ outf,
                                                 int mode)
{
    constexpr int MT = BM / 32;          // m-frags per wave
    constexpr int NA = BM / 32;          // A chunks per thread (4 @128, 2 @64)

    __shared__ unsigned short As[2][BM * 64];
    __shared__ unsigned short Bs[2][128 * 64];

    const int t = threadIdx.x;
    const int w = t >> 6, l = t & 63;
    const int lane16 = l & 15, quad = l >> 4;
    const int m0 = blockIdx.x * BM, n0 = blockIdx.y * 128;
    const int wm = (w & 1) * (BM / 2), wn = (w >> 1) * 64;

    f32x4 acc[MT][4] = {};

    // staging decode (NA A-chunks + 4 B-chunks per thread)
    int arow[NA], akcg[NA];
#pragma unroll
    for (int j = 0; j < NA; ++j) {
        const int c = t + j * 256;
        arow[j] = c >> 3;
        akcg[j] = (c & 7) ^ (arow[j] & 7);
    }
    int srow[4], skcg[4];
#pragma unroll
    for (int j = 0; j < 4; ++j) {
        const int c = t + j * 256;
        srow[j] = c >> 3;
        skcg[j] = (c & 7) ^ (srow[j] & 7);
    }

    // prologue: stage tile 0 into buffer 0, then one drain+barrier
#pragma unroll
    for (int j = 0; j < NA; ++j)
        gload16(A + (size_t)(m0 + arow[j]) * DD + akcg[j] * 8, &As[0][(t + j * 256) * 8]);
#pragma unroll
    for (int j = 0; j < 4; ++j)
        gload16(Bt + (size_t)(n0 + srow[j]) * DD + skcg[j] * 8, &Bs[0][(t + j * 256) * 8]);
    __syncthreads();

#pragma unroll 2
    for (int kt = 0; kt < 16; ++kt) {
        const int cur = kt & 1;
        // issue next tile's stage FIRST — latency hides under this tile's compute
        if (kt + 1 < 16) {
            const int k1 = (kt + 1) * 64;
#pragma unroll
            for (int j = 0; j < NA; ++j)
                gload16(A + (size_t)(m0 + arow[j]) * DD + k1 + akcg[j] * 8, &As[cur ^ 1][(t + j * 256) * 8]);
#pragma unroll
            for (int j = 0; j < 4; ++j)
                gload16(Bt + (size_t)(n0 + srow[j]) * DD + k1 + skcg[j] * 8, &Bs[cur ^ 1][(t + j * 256) * 8]);
        }
        // compute tile kt from buf[cur]
#pragma unroll
        for (int h = 0; h < 2; ++h) {
            bf16x8 af[MT], bfr[4];
#pragma unroll
            for (int mt = 0; mt < MT; ++mt) {
                const int row = wm + mt * 16 + lane16;
                af[mt] = *(const bf16x8*)&As[cur][(row * 8 + ((h * 4 + quad) ^ (row & 7))) * 8];
            }
#pragma unroll
            for (int nt = 0; nt < 4; ++nt) {
                const int row = wn + nt * 16 + lane16;
                bfr[nt] = *(const bf16x8*)&Bs[cur][(row * 8 + ((h * 4 + quad) ^ (row & 7))) * 8];
            }
#pragma unroll
            for (int mt = 0; mt < MT; ++mt)
#pragma unroll
                for (int nt = 0; nt < 4; ++nt)
                    acc[mt][nt] = __builtin_amdgcn_mfma_f32_16x16x32_bf16(af[mt], bfr[nt], acc[mt][nt], 0, 0, 0);
        }
        __syncthreads();
    }

    if (mode == 0) {
        const int which = n0 >> 10;
        const float* bias = which == 0 ? bias0 : which == 1 ? bias1 : bias2;
#pragma unroll
        for (int nt = 0; nt < 4; ++nt) {
            const int gcol = n0 + wn + nt * 16 + lane16;
            const int cd = gcol & 1023;
            const float bv = bias[cd];
            const int h_ = cd >> 6, d = cd & 63;
            if (which == 2) {
#pragma unroll
                for (int mt = 0; mt < MT; ++mt) {
                    const int row0 = m0 + wm + mt * 16 + quad * 4;
                    const int b_ = row0 >> 11, s0 = row0 & 2047;
                    union { unsigned short u[4]; uint2 v; } pk;
#pragma unroll
                    for (int r = 0; r < 4; ++r) pk.u[r] = f2bf(acc[mt][nt][r] + bv);
                    *(uint2*)(Vb + ((size_t)(b_ * HH + h_) * HD + d) * SS + s0) = pk.v;
                }
            } else {
                unsigned short* dst3 = which == 0 ? Qb : Kb;
                const float sc_ = which == 0 ? QSCALE : 1.0f;
#pragma unroll
                for (int mt = 0; mt < MT; ++mt)
#pragma unroll
                    for (int r = 0; r < 4; ++r) {
                        const int row = m0 + wm + mt * 16 + quad * 4 + r;
                        const int b_ = row >> 11, s_ = row & 2047;
                        dst3[(((size_t)(b_ * HH + h_) * SS + s_) * HD) + d] =
                            f2bf((acc[mt][nt][r] + bv) * sc_);
                    }
            }
        }
    } else {
#pragma unroll
        for (int nt = 0; nt < 4; ++nt) {
            const int gcol = n0 + wn + nt * 16 + lane16;
            const float bv = bias0[gcol];
#pragma unroll
            for (int mt = 0; mt < MT; ++mt)
#pragma unroll
                for (int r = 0; r < 4; ++r) {
                    const int row = m0 + wm + mt * 16 + quad * 4 + r;
                    outf[(size_t)row * DD + gcol] = acc[mt][nt][r] + bv;
                }
        }
    }
}

// ---------------------------------------------------------------------------
// MFMA flash attention v10 (r11 verified): T14 reg-staged K/V ring with
// LDS-only barriers; 32x32x16 swapped-operand MFMA; in-register softmax
// (T12 cvt_pk+permlane); fixed-max log2 softmax; parity k-split; softmax
// denominator on the MFMA pipe (ones-trick).
// ---------------------------------------------------------------------------
__global__ __launch_bounds__(512) void attn_mfma(const unsigned short* __restrict__ Q,
                                                 const unsigned short* __restrict__ K,
                                                 const unsigned short* __restrict__ V,
                                                 unsigned short* __restrict__ ctx)
{
    __shared__ unsigned short Ks[4][4096];   // [tile&3][row 64][8 chunks swizzled]
    __shared__ unsigned short Vs[4][4096];   // [tile&3][d 64][8 chunks swizzled]

    const int t = threadIdx.x;
    const int w = t >> 6, l = t & 63;
    const int l31 = l & 31, hi = l >> 5;
    const int qg = w & 3, par = w >> 2;            // q-group, k-parity
    const int bid = blockIdx.x;
    const int halfg = bid >> 8, idx = bid & 255;
    const int qb_ = idx >> 5;                      // 0..7
    const int qblk = halfg ? qb_ : 15 - qb_;       // pair (15-k, k) per CU
    const int hb = idx & 31;
    const int h = hb & 15, b = hb >> 4;
    const int q0 = qblk * 128;
    const size_t bh = (size_t)(b * HH + h) * SS;
    const unsigned short* Vg = V + (size_t)(b * HH + h) * HD * SS;

    const int wq0 = q0 + qg * 32;                  // this q-group's 32 rows
    // Q B-frags: lane holds Q[wq0 + l31][dt*16 + hi*8 .. +7]
    bf16x8 qf[4];
#pragma unroll
    for (int dt = 0; dt < 4; ++dt)
        qf[dt] = *(const bf16x8*)(Q + (bh + wq0 + l31) * HD + dt * 16 + hi * 8);

    // all-ones bf16 A-frag for the l-reduction MFMA
    bf16x8 ones;
#pragma unroll
    for (int i = 0; i < 8; ++i) ones[i] = (short)0x3F80;

    f32x16 ot[2] = {};                             // O^T: [d-half][16 regs], q = l31
    f32x16 lacc = {};                              // l: all 16 regs equal, col = l31

    const int ntiles = 2 * qblk + 2;               // always even
    // staging: 512 chunks of 16B per (tensor,tile), exactly 1 per thread
    const int sr = t >> 3;                         // row (K) / d (V)
    const int sg = (t & 7) ^ (sr & 7);             // swizzled k-chunk

    {   // prologue: reg-load + ds_write tiles 0 and 1
        uint4 ka  = *(const uint4*)(K + (bh + sr) * HD + sg * 8);
        uint4 kb2 = *(const uint4*)(K + (bh + 64 + sr) * HD + sg * 8);
        uint4 va  = *(const uint4*)(Vg + (size_t)sr * SS + sg * 8);
        uint4 vb2 = *(const uint4*)(Vg + (size_t)sr * SS + 64 + sg * 8);
        *(uint4*)&Ks[0][t * 8] = ka;
        *(uint4*)&Ks[1][t * 8] = kb2;
        *(uint4*)&Vs[0][t * 8] = va;
        *(uint4*)&Vs[1][t * 8] = vb2;
    }
    asm volatile("s_waitcnt lgkmcnt(0)" ::: "memory");
    __builtin_amdgcn_sched_barrier(0);
    __builtin_amdgcn_s_barrier();

    const int nsup = ntiles >> 1;
    for (int st = 0; st < nsup; ++st) {
        // (a) issue next 2 tiles' global loads into registers — no wait
        uint4 ka, kb2, va, vb2;
        const bool pre = (2 * st + 2 < ntiles);
        if (pre) {
            const int kaof = (2 * st + 2) * 64, kbof = kaof + 64;
            ka  = *(const uint4*)(K + (bh + kaof + sr) * HD + sg * 8);
            kb2 = *(const uint4*)(K + (bh + kbof + sr) * HD + sg * 8);
            va  = *(const uint4*)(Vg + (size_t)sr * SS + kaof + sg * 8);
            vb2 = *(const uint4*)(Vg + (size_t)sr * SS + kbof + sg * 8);
        }
        __builtin_amdgcn_sched_barrier(0);         // pin: loads issued before compute

        // (b) compute this wave's parity tile from the ring
        const int mt = 2 * st + par;
        const int k0 = mt * 64;
        if (k0 <= wq0 + 31) {                      // not fully causal-masked
            const unsigned short* Kt = Ks[mt & 3];
            const unsigned short* Vt = Vs[mt & 3];

            // S^T = K Q (log2-scaled already); two 32-k halves interleaved
            f32x16 s[2] = {};
            __builtin_amdgcn_s_setprio(1);
#pragma unroll
            for (int dt = 0; dt < 4; ++dt) {
#pragma unroll
                for (int kh = 0; kh < 2; ++kh) {
                    const int row = kh * 32 + l31;
                    bf16x8 kf = *(const bf16x8*)&Kt[(row * 8 + ((dt * 2 + hi) ^ (row & 7))) * 8];
                    s[kh] = __builtin_amdgcn_mfma_f32_32x32x16_bf16(kf, qf[dt], s[kh], 0, 0, 0);
                }
            }
            __builtin_amdgcn_s_setprio(0);

            // causal mask on diagonal tiles: k = k0 + kh*32 + (r&3)+8*(r>>2)+4*hi
            if (k0 + 63 > wq0) {
                const int q = wq0 + l31;
#pragma unroll
                for (int kh = 0; kh < 2; ++kh)
#pragma unroll
                    for (int r = 0; r < 16; ++r) {
                        const int k = k0 + kh * 32 + (r & 3) + 8 * (r >> 2) + 4 * hi;
                        if (k > q) s[kh][r] = -1e30f;
                    }
            }

            // p = exp2(s) in place (sum deferred to the ones-MFMA)
#pragma unroll
            for (int kh = 0; kh < 2; ++kh)
#pragma unroll
                for (int r = 0; r < 16; ++r) s[kh][r] = __builtin_amdgcn_exp2f(s[kh][r]);

            // P -> A-frag redistribution (T12) + PV + l, per 16-k chunk
#pragma unroll
            for (int kh = 0; kh < 2; ++kh) {
#pragma unroll
                for (int c = 0; c < 2; ++c) {
                    const int rb = c * 8;
                    unsigned int w0, w1, w2, w3;
                    asm("v_cvt_pk_bf16_f32 %0, %1, %2" : "=v"(w0) : "v"(s[kh][rb + 0]), "v"(s[kh][rb + 1]));
                    asm("v_cvt_pk_bf16_f32 %0, %1, %2" : "=v"(w2) : "v"(s[kh][rb + 4]), "v"(s[kh][rb + 5]));
                    asm("v_cvt_pk_bf16_f32 %0, %1, %2" : "=v"(w1) : "v"(s[kh][rb + 2]), "v"(s[kh][rb + 3]));
                    asm("v_cvt_pk_bf16_f32 %0, %1, %2" : "=v"(w3) : "v"(s[kh][rb + 6]), "v"(s[kh][rb + 7]));
                    asm("v_permlane32_swap_b32 %0, %1" : "+v"(w0), "+v"(w2));
                    asm("v_permlane32_swap_b32 %0, %1" : "+v"(w1), "+v"(w3));
                    union { unsigned int u[4]; bf16x8 v; } pa;
                    pa.u[0] = w0; pa.u[1] = w1; pa.u[2] = w2; pa.u[3] = w3;
                    const int chunk = kh * 4 + c * 2 + hi;
                    const int rlo = l31, rhi2 = 32 + l31;
                    bf16x8 v0 = *(const bf16x8*)&Vt[(rlo * 8 + (chunk ^ (rlo & 7))) * 8];
                    bf16x8 v1 = *(const bf16x8*)&Vt[(rhi2 * 8 + (chunk ^ (rhi2 & 7))) * 8];
                    __builtin_amdgcn_s_setprio(1);
                    ot[0] = __builtin_amdgcn_mfma_f32_32x32x16_bf16(v0, pa.v, ot[0], 0, 0, 0);
                    ot[1] = __builtin_amdgcn_mfma_f32_32x32x16_bf16(v1, pa.v, ot[1], 0, 0, 0);
                    lacc  = __builtin_amdgcn_mfma_f32_32x32x16_bf16(ones, pa.v, lacc, 0, 0, 0);
                    __builtin_amdgcn_s_setprio(0);
                }
            }
        }

        // (c) write staged regs to the ring (vmcnt wait auto-inserted here,
        //     hidden under the compute above), then LDS-only barrier
        if (pre) {
            const int ba = (2 * st + 2) & 3, bb3 = (2 * st + 3) & 3;
            *(uint4*)&Ks[ba][t * 8] = ka;
            *(uint4*)&Ks[bb3][t * 8] = kb2;
            *(uint4*)&Vs[ba][t * 8] = va;
            *(uint4*)&Vs[bb3][t * 8] = vb2;
        }
        asm volatile("s_waitcnt lgkmcnt(0)" ::: "memory");
        __builtin_amdgcn_sched_barrier(0);
        __builtin_amdgcn_s_barrier();
    }

    // l for this wave's tiles: any reg of lacc (all 16 equal; both halves full)
    float lp = lacc[0];

    // ---- parity combine: O_total = O_p0 + O_p1, l_total = l_p0 + l_p1 ----
    float* Osh = (float*)&Ks[0][0];                // 4 qg x 32 regs x 64 lanes = 32KB
    float* Lsh = (float*)&Vs[0][0];                // 4 qg x 64 lanes
    if (par == 1) {
#pragma unroll
        for (int a2 = 0; a2 < 2; ++a2)
#pragma unroll
            for (int r = 0; r < 16; ++r) Osh[qg * 2048 + (a2 * 16 + r) * 64 + l] = ot[a2][r];
        Lsh[qg * 64 + l] = lp;
    }
    __syncthreads();
    if (par == 0) {
#pragma unroll
        for (int a2 = 0; a2 < 2; ++a2)
#pragma unroll
            for (int r = 0; r < 16; ++r) ot[a2][r] += Osh[qg * 2048 + (a2 * 16 + r) * 64 + l];
        lp += Lsh[qg * 64 + l];

        const float inv = 1.f / lp;

        const int qrow = wq0 + l31;
        unsigned short* dst = ctx + ((size_t)(b * SS) + qrow) * DD + h * HD;
#pragma unroll
        for (int a2 = 0; a2 < 2; ++a2)
#pragma unroll
            for (int u = 0; u < 4; ++u) {
                const int d0 = a2 * 32 + 8 * u + 4 * hi;
                union { unsigned short u4[4]; uint2 v; } pk;
#pragma unroll
                for (int r = 0; r < 4; ++r) pk.u4[r] = f2bf(ot[a2][4 * u + r] * inv);
                *(uint2*)(dst + d0) = pk.v;
            }
    }
}

// ---------------------------------------------------------------------------
extern "C" void kernel_launch(void* const* d_in, const int* in_sizes, int n_in,
                              void* d_out, int out_size, void* d_ws, size_t ws_size,
                              hipStream_t stream) {
    const float* x  = (const float*)d_in[0];
    const float* Wq = (const float*)d_in[1];
    const float* bq = (const float*)d_in[2];
    const float* Wk = (const float*)d_in[3];
    const float* bk = (const float*)d_in[4];
    const float* Wv = (const float*)d_in[5];
    const float* bv = (const float*)d_in[6];
    const float* Wo = (const float*)d_in[7];
    const float* bo = (const float*)d_in[8];
    float* out = (float*)d_out;

    unsigned short* xb  = (unsigned short*)d_ws;
    unsigned short* Wt  = xb  + (size_t)MM * DD;
    unsigned short* Qb  = Wt  + (size_t)4 * DD * DD;
    unsigned short* Kb  = Qb  + (size_t)MM * DD;
    unsigned short* Vb  = Kb  + (size_t)MM * DD;
    unsigned short* ctxb = Vb + (size_t)MM * DD;

    prep_kernel<<<2048 + 1024, 256, 0, stream>>>(x, Wq, Wk, Wv, Wo, xb, Wt);

    gemm_mfma<128><<<dim3(MM / 128, 3072 / 128), 256, 0, stream>>>(
        xb, Wt, bq, bk, bv, Qb, Kb, Vb, nullptr, 0);

    attn_mfma<<<(SS / 128) * HH * BB, 512, 0, stream>>>(Qb, Kb, Vb, ctxb);

    gemm_mfma<64><<<dim3(MM / 64, DD / 128), 256, 0, stream>>>(
        ctxb, Wt + (size_t)3 * DD * DD, bo, nullptr, nullptr,
        nullptr, nullptr, nullptr, out, 1);
}